// Round 16
// baseline (40329.025 us; speedup 1.0000x reference)
//
#include <hip/hip_runtime.h>
#include <cstdint>

#define T_STEPS 8192
#define HDIM    1024
#define NBLK    256
#define NTHR    256

typedef float        f32x4 __attribute__((ext_vector_type(4)));
typedef unsigned int u32x4 __attribute__((ext_vector_type(4)));

__device__ __forceinline__ float dot4(f32x4 a, f32x4 b) {
    return a[0] * b[0] + a[1] * b[1] + a[2] * b[2] + a[3] * b[3];
}
__device__ __forceinline__ float sigmoidf_(float v) { return 1.0f / (1.0f + __expf(-v)); }
__device__ __forceinline__ float tanhf_(float v)    { return 1.0f - 2.0f / (__expf(2.0f * v) + 1.0f); }
__device__ __forceinline__ unsigned bf16_rne(float f) {
    unsigned b = __float_as_uint(f);
    return (b + 0x7FFFu + ((b >> 16) & 1u)) >> 16;
}

// 64-lane sum via DPP (VALU-speed, no LDS): row_shr 1/2/4/8 then
// row_bcast15/31. Result valid in lane 63 only. Replaces R8's 24-op
// ds_swizzle butterfly (6-deep ~40cy DS chains, unhidden at 1 wave/SIMD).
__device__ __forceinline__ float red64(float v) {
    v += __int_as_float(__builtin_amdgcn_update_dpp(
            0, __float_as_int(v), 0x111, 0xF, 0xF, false));  // row_shr:1
    v += __int_as_float(__builtin_amdgcn_update_dpp(
            0, __float_as_int(v), 0x112, 0xF, 0xF, false));  // row_shr:2
    v += __int_as_float(__builtin_amdgcn_update_dpp(
            0, __float_as_int(v), 0x114, 0xF, 0xF, false));  // row_shr:4
    v += __int_as_float(__builtin_amdgcn_update_dpp(
            0, __float_as_int(v), 0x118, 0xF, 0xF, false));  // row_shr:8
    v += __int_as_float(__builtin_amdgcn_update_dpp(
            0, __float_as_int(v), 0x142, 0xF, 0xF, false));  // row_bcast:15
    v += __int_as_float(__builtin_amdgcn_update_dpp(
            0, __float_as_int(v), 0x143, 0xF, 0xF, false));  // row_bcast:31
    return v;   // lane 63 = full sum
}

// R8 chassis (22.3ms best): same geometry, same weights/pins, same
// writer-private ring lines, same (epoch16<<16)|bf16 payload, same
// publish->xprefetch->gxp->poll-late order. ONLY two deltas:
//  1. shuffle butterfly -> DPP reduce (lane 63 owns the result)
//  2. LDS+__syncthreads rebroadcast -> each lane polls its own 4 ring
//     lines {l,l+64,l+128,l+192} (= exactly h[4l+256i..+3]) with 4 loads
//     + ONE vmcnt(0), unpacking straight into hr. No LDS, no barrier —
//     waves decouple, 2-slot parity safety holds per-wave.
__global__ __launch_bounds__(NTHR, 1)
void lstm_persistent(const float* __restrict__ x,
                     const float* __restrict__ W_ih,
                     const float* __restrict__ W_hh,
                     const float* __restrict__ b_ih,
                     const float* __restrict__ b_hh,
                     const float* __restrict__ h0,
                     const float* __restrict__ c0,
                     float* __restrict__ out,
                     unsigned int* __restrict__ ring)
{
    const int tid = threadIdx.x;
    const int w   = tid >> 6;   // wave 0..3
    const int l   = tid & 63;   // lane
    const int u   = (blockIdx.x << 2) + w;

    // ---- weights: lane l covers elements 4l + 256i (+j) — R8-identical ----
    f32x4 whh[16], wih[16];
#pragma unroll
    for (int q = 0; q < 4; ++q) {
        const float* rh = W_hh + (size_t)(q * HDIM + u) * HDIM + 4 * l;
        const float* ri = W_ih + (size_t)(q * HDIM + u) * HDIM + 4 * l;
#pragma unroll
        for (int i = 0; i < 4; ++i) {
            whh[q * 4 + i] = *(const f32x4*)(rh + 256 * i);
            wih[q * 4 + i] = *(const f32x4*)(ri + 256 * i);
        }
    }
#pragma unroll
    for (int k = 0; k < 16; ++k) {
        asm volatile("" : "+v"(whh[k]));
        asm volatile("" : "+v"(wih[k]));
    }

    float bias[4];
#pragma unroll
    for (int q = 0; q < 4; ++q) bias[q] = b_ih[q * HDIM + u] + b_hh[q * HDIM + u];
    float c = c0[u];

    f32x4 hr[4];
#pragma unroll
    for (int i = 0; i < 4; ++i) hr[i] = *(const f32x4*)(h0 + 4 * l + 256 * i);

    float gxp[4];
    {
        f32x4 x0[4];
#pragma unroll
        for (int i = 0; i < 4; ++i) x0[i] = *(const f32x4*)(x + 4 * l + 256 * i);
#pragma unroll
        for (int q = 0; q < 4; ++q) {
            float a = 0.f;
#pragma unroll
            for (int i = 0; i < 4; ++i) a += dot4(wih[q * 4 + i], x0[i]);
            gxp[q] = a;
        }
    }
    f32x4 xr[4], xn[4];
#pragma unroll
    for (int i = 0; i < 4; ++i) xr[i] = *(const f32x4*)(x + HDIM + 4 * l + 256 * i);

    const unsigned long long ringb = (unsigned long long)ring;

    for (int t = 0; t < T_STEPS; ++t) {
        // gates = gxp + Whh . h_{t-1}; reduce to lane 63 via DPP
        float acc[4];
#pragma unroll
        for (int q = 0; q < 4; ++q) {
            float a = gxp[q];
#pragma unroll
            for (int i = 0; i < 4; ++i) a += dot4(whh[q * 4 + i], hr[i]);
            acc[q] = red64(a);
        }
        // gates valid on lane 63 only (other lanes harmless garbage)
        const float gi = sigmoidf_(acc[0] + bias[0]);
        const float gf = sigmoidf_(acc[1] + bias[1]);
        const float gg = tanhf_   (acc[2] + bias[2]);
        const float go = sigmoidf_(acc[3] + bias[3]);
        c = gf * c + gi * gg;
        const float hval = go * tanhf_(c);

        if (l == 63) {
            // publish into this block's private 64B line (R8 layout)
            const unsigned pk = ((unsigned)(t + 1) << 16) | bf16_rne(hval);
            unsigned int* slot = ring + (((t & 1) * NBLK + blockIdx.x) << 4) + w;
            asm volatile("global_store_dword %0, %1, off sc0 sc1"
                         :: "v"((unsigned long long)slot), "v"(pk) : "memory");
        }
        if (t == T_STEPS - 1) {
            if (l == 63) out[(size_t)t * HDIM + u] = hval;
            break;
        }

        // x[t+2] prefetch (R8 position: before poll)
        {
            const int tn = (t + 2 < T_STEPS) ? (t + 2) : (T_STEPS - 1);
            const float* xp = x + (size_t)tn * HDIM;
#pragma unroll
            for (int i = 0; i < 4; ++i) xn[i] = *(const f32x4*)(xp + 4 * l + 256 * i);
        }
        // gxp filler for t+1 (R8 position: between publish and poll)
#pragma unroll
        for (int q = 0; q < 4; ++q) {
            float a = 0.f;
#pragma unroll
            for (int i = 0; i < 4; ++i) a += dot4(wih[q * 4 + i], xr[i]);
            gxp[q] = a;
        }

        // poll: lane l reads its 4 lines {l,l+64,l+128,l+192} directly
        {
            const unsigned e = (unsigned)(t + 1);
            const unsigned long long a0 =
                ringb + (unsigned long long)((t & 1) * 16384 + (l << 6));
            const unsigned long long a1 = a0 + 4096;
            const unsigned long long a2 = a0 + 8192;
            const unsigned long long a3 = a0 + 12288;
            u32x4 p0, p1, p2, p3;
            for (;;) {
                asm volatile(
                    "global_load_dwordx4 %0, %4, off sc0 sc1\n\t"
                    "global_load_dwordx4 %1, %5, off sc0 sc1\n\t"
                    "global_load_dwordx4 %2, %6, off sc0 sc1\n\t"
                    "global_load_dwordx4 %3, %7, off sc0 sc1\n\t"
                    "s_waitcnt vmcnt(0)"
                    : "=&v"(p0), "=&v"(p1), "=&v"(p2), "=&v"(p3)
                    : "v"(a0), "v"(a1), "v"(a2), "v"(a3)
                    : "memory");
                unsigned bad = (p0[0] >> 16) ^ e;
                bad |= (p0[1] >> 16) ^ e;  bad |= (p0[2] >> 16) ^ e;
                bad |= (p0[3] >> 16) ^ e;  bad |= (p1[0] >> 16) ^ e;
                bad |= (p1[1] >> 16) ^ e;  bad |= (p1[2] >> 16) ^ e;
                bad |= (p1[3] >> 16) ^ e;  bad |= (p2[0] >> 16) ^ e;
                bad |= (p2[1] >> 16) ^ e;  bad |= (p2[2] >> 16) ^ e;
                bad |= (p2[3] >> 16) ^ e;  bad |= (p3[0] >> 16) ^ e;
                bad |= (p3[1] >> 16) ^ e;  bad |= (p3[2] >> 16) ^ e;
                bad |= (p3[3] >> 16) ^ e;
                if (bad == 0u) break;
            }
            // unpack straight into hr (bf16 -> f32): hr[i] = h[256i+4l .. +3]
#pragma unroll
            for (int j = 0; j < 4; ++j) hr[0][j] = __uint_as_float(p0[j] << 16);
#pragma unroll
            for (int j = 0; j < 4; ++j) hr[1][j] = __uint_as_float(p1[j] << 16);
#pragma unroll
            for (int j = 0; j < 4; ++j) hr[2][j] = __uint_as_float(p2[j] << 16);
#pragma unroll
            for (int j = 0; j < 4; ++j) hr[3][j] = __uint_as_float(p3[j] << 16);
        }
        // out store AFTER detect — off the poll-drain scope
        if (l == 63) out[(size_t)t * HDIM + u] = hval;
#pragma unroll
        for (int i = 0; i < 4; ++i) xr[i] = xn[i];
    }
}

extern "C" void kernel_launch(void* const* d_in, const int* in_sizes, int n_in,
                              void* d_out, int out_size, void* d_ws, size_t ws_size,
                              hipStream_t stream)
{
    const float* x    = (const float*)d_in[0];
    const float* W_ih = (const float*)d_in[1];
    const float* W_hh = (const float*)d_in[2];
    const float* b_ih = (const float*)d_in[3];
    const float* b_hh = (const float*)d_in[4];
    const float* h0   = (const float*)d_in[5];
    const float* c0   = (const float*)d_in[6];

    unsigned int* ring = (unsigned int*)d_ws;
    hipMemsetAsync(d_ws, 0, 2 * NBLK * 16 * sizeof(unsigned int), stream);
    lstm_persistent<<<NBLK, NTHR, 0, stream>>>(x, W_ih, W_hh, b_ih, b_hh, h0, c0,
                                               (float*)d_out, ring);
}